// Round 8
// baseline (627.494 us; speedup 1.0000x reference)
//
#include <hip/hip_runtime.h>
#include <hip/hip_bf16.h>
#include <math.h>

// Problem constants (fixed by the reference)
#define B_TOK 8192
#define IN_DIM 4096
#define HID 2048
#define NE 64
#define TOPK 8

typedef __attribute__((ext_vector_type(8))) _Float16 f16x8;
typedef __attribute__((ext_vector_type(4))) float f32x4;

#define AS1 __attribute__((address_space(1)))
#define AS3 __attribute__((address_space(3)))

#define BM 128
#define BN 128
#define BK 32

// ---------------------------------------------------------------------------
// Prep: split W2 [2048,64] and nw [4096,64] into fp16 hi/lo, transposed to
// [col][k]. Blocks 0-63: W2 col; blocks 64-127: nw col.
// ---------------------------------------------------------------------------
__global__ __launch_bounds__(256) void k_prep_w(
    const float* __restrict__ W2, const float* __restrict__ nw,
    _Float16* __restrict__ w2h, _Float16* __restrict__ w2l,
    _Float16* __restrict__ nwh, _Float16* __restrict__ nwl) {
  const int b = blockIdx.x;
  if (b < NE) {
    const int c = b;
    for (int k = threadIdx.x; k < HID; k += 256) {
      const float v = W2[(size_t)k * NE + c];
      const _Float16 hi = (_Float16)v;
      w2h[(size_t)c * HID + k] = hi;
      w2l[(size_t)c * HID + k] = (_Float16)(v - (float)hi);
    }
  } else {
    const int c = b - NE;
    for (int k = threadIdx.x; k < IN_DIM; k += 256) {
      const float v = nw[(size_t)k * NE + c];
      const _Float16 hi = (_Float16)v;
      nwh[(size_t)c * IN_DIM + k] = hi;
      nwl[(size_t)c * IN_DIM + k] = (_Float16)(v - (float)hi);
    }
  }
}

// ---------------------------------------------------------------------------
// Prep: W1 image — split fp16 hi/lo, tiled per (colblk c, ktile kt), swizzled
// exactly like the BsH/BsL LDS layout:
//   img[(c*128 + kt)*4096 + n*32 + ((g ^ sw(n))<<3) + j]
//     = split(W1[kt*32 + g*8 + j][c*128 + n]),  sw(n) = (n>>1)&3.
// ---------------------------------------------------------------------------
__global__ __launch_bounds__(256) void k_prep_w1img(
    const float* __restrict__ W1, _Float16* __restrict__ imgH,
    _Float16* __restrict__ imgL) {
  const int c = blockIdx.x;   // 0..15
  const int kt = blockIdx.y;  // 0..127
  const int tid = threadIdx.x;
  const int n = tid & 127;
  const int g0 = tid >> 7;  // 0..1
  const size_t base = ((size_t)c * (IN_DIM / 32) + kt) * 4096;
  const int sw = (n >> 1) & 3;
#pragma unroll
  for (int gi = 0; gi < 2; ++gi) {
    const int g = g0 * 2 + gi;  // 0..3
    const float* src = &W1[(size_t)(kt * 32 + g * 8) * HID + c * 128 + n];
    f16x8 vh, vl;
#pragma unroll
    for (int j = 0; j < 8; ++j) {
      const float v = src[(size_t)j * HID];
      const _Float16 hi = (_Float16)v;
      vh[j] = hi;
      vl[j] = (_Float16)(v - (float)hi);
    }
    const size_t off = base + n * 32 + ((g ^ sw) << 3);
    *(f16x8*)&imgH[off] = vh;
    *(f16x8*)&imgL[off] = vl;
  }
}

// ---------------------------------------------------------------------------
// Prep: x image — split fp16 hi/lo, tiled per (rowblk rb, ktile kt),
// swizzled exactly like the As LDS layout (also the per-lane A-frag layout).
// ---------------------------------------------------------------------------
__global__ __launch_bounds__(256) void k_prep_ximg(
    const float* __restrict__ x, _Float16* __restrict__ imgH,
    _Float16* __restrict__ imgL) {
  const int rb = blockIdx.x;  // 0..63
  const int kt = blockIdx.y;  // 0..127
  const int tid = threadIdx.x;
  const int ar = tid >> 1;    // 0..127
  const int half = tid & 1;   // 0..1
  const size_t base = ((size_t)rb * (IN_DIM / 32) + kt) * 4096;
  const int sw = (ar >> 1) & 3;
  const float* src = &x[(size_t)(rb * 128 + ar) * IN_DIM + kt * 32 + half * 16];
#pragma unroll
  for (int gi = 0; gi < 2; ++gi) {
    const int g = half * 2 + gi;  // 0..3
    const float4 f0 = *(const float4*)(src + gi * 8);
    const float4 f1 = *(const float4*)(src + gi * 8 + 4);
    const float fv[8] = {f0.x, f0.y, f0.z, f0.w, f1.x, f1.y, f1.z, f1.w};
    f16x8 vh, vl;
#pragma unroll
    for (int j = 0; j < 8; ++j) {
      const _Float16 hi = (_Float16)fv[j];
      vh[j] = hi;
      vl[j] = (_Float16)(fv[j] - (float)hi);
    }
    const size_t off = base + ar * 32 + ((g ^ sw) << 3);
    *(f16x8*)&imgH[off] = vh;
    *(f16x8*)&imgL[off] = vl;
  }
}

// ---------------------------------------------------------------------------
// GEMM1 (path A): A-fragments loaded global->register directly from the
// x image (per-lane addresses ARE the image layout; coalesced 1KB per frag).
// aH reg-double-buffered (1-phase prefetch), aL single-buffered (issued at
// phase start, first used ~32 MFMA later). B LDS-double-buffered via
// global_load_lds with counted vmcnt(12) = {4 B-lds + 4 aH + 4 aL}/phase.
// LDS 32KB (was 128KB) -> 3 blocks/CU target via __launch_bounds__(256,3).
// ---------------------------------------------------------------------------
#define WAITVM12() asm volatile("s_waitcnt vmcnt(12)" ::: "memory")
#define WAITVM4() asm volatile("s_waitcnt vmcnt(4)" ::: "memory")
#define BAR()                      \
  do {                             \
    asm volatile("" ::: "memory"); \
    __builtin_amdgcn_s_barrier();  \
    asm volatile("" ::: "memory"); \
  } while (0)

__global__ __launch_bounds__(256, 3) void k_gemm1_reg(
    const _Float16* __restrict__ ximgH, const _Float16* __restrict__ ximgL,
    const _Float16* __restrict__ w1ih, const _Float16* __restrict__ w1il,
    const float* __restrict__ b1, float* __restrict__ h) {
  __shared__ _Float16 BsH0[BN * BK], BsL0[BN * BK];
  __shared__ _Float16 BsH1[BN * BK], BsL1[BN * BK];

  const int tid = threadIdx.x;
  const int lane = tid & 63;
  const int w = tid >> 6;
  const int wr = (w >> 1) << 6;
  const int wc = (w & 1) << 6;

  // XCD-aware remap: f%8 = XCD; chunk of 128 logical blocks per XCD.
  const int f = blockIdx.x;
  const int L = (f & 7) * 128 + (f >> 3);
  const int brow = L >> 4;  // 0..63
  const int bcol = L & 15;  // 0..15
  const int row0 = brow * BM;

  const int fr = lane & 15;
  const int kg = lane >> 4;
  int aoff[4], boff[4];
#pragma unroll
  for (int m = 0; m < 4; ++m) {
    const int r = wr + m * 16 + fr;
    aoff[m] = r * BK + ((kg ^ ((r >> 1) & 3)) << 3);
  }
#pragma unroll
  for (int n = 0; n < 4; ++n) {
    const int c = wc + n * 16 + fr;
    boff[n] = c * BK + ((kg ^ ((c >> 1) & 3)) << 3);
  }

  // A tile bases (f16 units); per-tile advance = 4096 f16
  const _Float16* aTH = ximgH + (size_t)brow * (IN_DIM / 32) * 4096;
  const _Float16* aTL = ximgL + (size_t)brow * (IN_DIM / 32) * 4096;
  // B staging source (byte pointers incl. per-lane 16B slot)
  const char* pbh = (const char*)w1ih +
                    ((size_t)bcol * (IN_DIM / 32) * 4096) * 2 + (lane << 4);
  const char* pbl = (const char*)w1il +
                    ((size_t)bcol * (IN_DIM / 32) * 4096) * 2 + (lane << 4);

#define STAGE_B(BH, BL, kt)                                                    \
  do {                                                                         \
    const size_t _tb = (size_t)(kt) * 8192;                                    \
    _Pragma("unroll") for (int i = 0; i < 2; ++i) {                            \
      const int cb = ((w << 1) + i) << 10;                                     \
      __builtin_amdgcn_global_load_lds(                                        \
          (const AS1 unsigned int*)(pbh + _tb + cb),                           \
          (AS3 unsigned int*)((char*)(BH) + cb), 16, 0, 0);                    \
      __builtin_amdgcn_global_load_lds(                                        \
          (const AS1 unsigned int*)(pbl + _tb + cb),                           \
          (AS3 unsigned int*)((char*)(BL) + cb), 16, 0, 0);                    \
    }                                                                          \
  } while (0)

#define LOAD_A4(dst, src, kt)                                                  \
  do {                                                                         \
    _Pragma("unroll") for (int m = 0; m < 4; ++m) dst[m] =                     \
        *(const f16x8*)&(src)[(size_t)(kt)*4096 + aoff[m]];                    \
  } while (0)

  f32x4 acc[4][4];
  const f32x4 zero = {0.f, 0.f, 0.f, 0.f};
#pragma unroll
  for (int m = 0; m < 4; ++m)
#pragma unroll
    for (int n = 0; n < 4; ++n) acc[m][n] = zero;

#define COMPUTE3(AH, AL, BH, BL)                                               \
  do {                                                                         \
    f16x8 bH[4], bL[4];                                                        \
    _Pragma("unroll") for (int n = 0; n < 4; ++n) bH[n] =                      \
        *(const f16x8*)&(BH)[boff[n]];                                         \
    _Pragma("unroll") for (int m = 0; m < 4; ++m)                              \
        _Pragma("unroll") for (int n = 0; n < 4; ++n) acc[m][n] =              \
            __builtin_amdgcn_mfma_f32_16x16x32_f16(AH[m], bH[n], acc[m][n], 0, \
                                                   0, 0);                      \
    _Pragma("unroll") for (int n = 0; n < 4; ++n) bL[n] =                      \
        *(const f16x8*)&(BL)[boff[n]];                                         \
    _Pragma("unroll") for (int m = 0; m < 4; ++m)                              \
        _Pragma("unroll") for (int n = 0; n < 4; ++n) acc[m][n] =              \
            __builtin_amdgcn_mfma_f32_16x16x32_f16(AH[m], bL[n], acc[m][n], 0, \
                                                   0, 0);                      \
    _Pragma("unroll") for (int m = 0; m < 4; ++m)                              \
        _Pragma("unroll") for (int n = 0; n < 4; ++n) acc[m][n] =              \
            __builtin_amdgcn_mfma_f32_16x16x32_f16(AL[m], bH[n], acc[m][n], 0, \
                                                   0, 0);                      \
  } while (0)

  f16x8 ahA[4], ahB[4], al[4];

  // prologue: tile 0 B -> buf0 (4 lds-loads), aH(0) -> ahA (4 reg-loads)
  STAGE_B(BsH0, BsL0, 0);
  LOAD_A4(ahA, aTH, 0);

  const int NT = IN_DIM / BK;  // 128, even
  for (int t = 0; t < NT; t += 2) {
    // phase 0: compute tile t from (ahA, buf0); prefetch t+1
    STAGE_B(BsH1, BsL1, t + 1);  // +4
    LOAD_A4(ahB, aTH, t + 1);    // +4
    LOAD_A4(al, aTL, t);         // +4 (used later this phase; auto-waited)
    WAITVM12();                  // tile-t B + aH landed (12 newest in flight)
    BAR();
    COMPUTE3(ahA, al, BsH0, BsL0);
    BAR();  // buf0 free
    // phase 1: compute tile t+1 from (ahB, buf1); prefetch t+2
    if (t + 2 < NT) {
      STAGE_B(BsH0, BsL0, t + 2);
      LOAD_A4(ahA, aTH, t + 2);
      LOAD_A4(al, aTL, t + 1);
      WAITVM12();
    } else {
      LOAD_A4(al, aTL, t + 1);
      WAITVM4();
    }
    BAR();
    COMPUTE3(ahB, al, BsH1, BsL1);
    BAR();  // buf1 free
  }

  const int crow = (lane >> 4) << 2;
  const int ccol = lane & 15;
  const int col0 = bcol * BN;
#pragma unroll
  for (int n = 0; n < 4; ++n) {
    const int gc = col0 + wc + n * 16 + ccol;
    const float bias = b1[gc];
#pragma unroll
    for (int m = 0; m < 4; ++m) {
      const int gr = row0 + wr + m * 16 + crow;
#pragma unroll
      for (int j = 0; j < 4; ++j)
        h[(size_t)(gr + j) * HID + gc] = fmaxf(acc[m][n][j] + bias, 0.f);
    }
  }
#undef STAGE_B
#undef LOAD_A4
#undef COMPUTE3
}

// ---------------------------------------------------------------------------
// GEMM1 (path B, R5-proven): B via image, A converted in-kernel.
// ---------------------------------------------------------------------------
__global__ __launch_bounds__(256) void k_gemm1_img(
    const float* __restrict__ x, const _Float16* __restrict__ w1ih,
    const _Float16* __restrict__ w1il, const float* __restrict__ b1,
    float* __restrict__ h) {
  __shared__ _Float16 AsH[BM * BK];
  __shared__ _Float16 AsL[BM * BK];
  __shared__ _Float16 BsH[BN * BK];
  __shared__ _Float16 BsL[BN * BK];

  const int tid = threadIdx.x;
  const int lane = tid & 63;
  const int w = tid >> 6;
  const int wr = (w >> 1) << 6;
  const int wc = (w & 1) << 6;
  const int row0 = blockIdx.y * BM;

  const int fr = lane & 15;
  const int kg = lane >> 4;
  int aoff[4], boff[4];
#pragma unroll
  for (int m = 0; m < 4; ++m) {
    const int r = wr + m * 16 + fr;
    aoff[m] = r * BK + ((kg ^ ((r >> 1) & 3)) << 3);
  }
#pragma unroll
  for (int n = 0; n < 4; ++n) {
    const int c = wc + n * 16 + fr;
    boff[n] = c * BK + ((kg ^ ((c >> 1) & 3)) << 3);
  }

  f32x4 acc[4][4];
  const f32x4 zero = {0.f, 0.f, 0.f, 0.f};
#pragma unroll
  for (int m = 0; m < 4; ++m)
#pragma unroll
    for (int n = 0; n < 4; ++n) acc[m][n] = zero;

  for (int k0 = 0; k0 < IN_DIM; k0 += BK) {
    __syncthreads();
    {
      const size_t tb =
          (((size_t)blockIdx.x * (IN_DIM / 32) + (k0 >> 5)) * 4096) *
          sizeof(_Float16);
      const char* gh = (const char*)w1ih + tb + (lane << 4);
      const char* gl = (const char*)w1il + tb + (lane << 4);
#pragma unroll
      for (int i = 0; i < 2; ++i) {
        const int cb = ((w << 1) + i) << 10;
        __builtin_amdgcn_global_load_lds((const AS1 unsigned int*)(gh + cb),
                                         (AS3 unsigned int*)((char*)BsH + cb),
                                         16, 0, 0);
        __builtin_amdgcn_global_load_lds((const AS1 unsigned int*)(gl + cb),
                                         (AS3 unsigned int*)((char*)BsL + cb),
                                         16, 0, 0);
      }
    }
#pragma unroll
    for (int i = 0; i < 2; ++i) {
      const int ar = (tid >> 2) + i * 64;
      const int g = tid & 3;
      const float* src = &x[(size_t)(row0 + ar) * IN_DIM + k0 + (g << 3)];
      const float4 f0 = *(const float4*)src;
      const float4 f1 = *(const float4*)(src + 4);
      const float fv[8] = {f0.x, f0.y, f0.z, f0.w, f1.x, f1.y, f1.z, f1.w};
      f16x8 vh, vl;
#pragma unroll
      for (int j = 0; j < 8; ++j) {
        const _Float16 hi = (_Float16)fv[j];
        vh[j] = hi;
        vl[j] = (_Float16)(fv[j] - (float)hi);
      }
      const int off = ar * BK + (((g ^ ((ar >> 1) & 3))) << 3);
      *(f16x8*)&AsH[off] = vh;
      *(f16x8*)&AsL[off] = vl;
    }
    __syncthreads();
    f16x8 aH[4], bH[4], bL[4], aL[4];
#pragma unroll
    for (int m = 0; m < 4; ++m) aH[m] = *(const f16x8*)&AsH[aoff[m]];
#pragma unroll
    for (int n = 0; n < 4; ++n) bH[n] = *(const f16x8*)&BsH[boff[n]];
#pragma unroll
    for (int m = 0; m < 4; ++m)
#pragma unroll
      for (int n = 0; n < 4; ++n)
        acc[m][n] = __builtin_amdgcn_mfma_f32_16x16x32_f16(aH[m], bH[n],
                                                           acc[m][n], 0, 0, 0);
#pragma unroll
    for (int n = 0; n < 4; ++n) bL[n] = *(const f16x8*)&BsL[boff[n]];
#pragma unroll
    for (int m = 0; m < 4; ++m)
#pragma unroll
      for (int n = 0; n < 4; ++n)
        acc[m][n] = __builtin_amdgcn_mfma_f32_16x16x32_f16(aH[m], bL[n],
                                                           acc[m][n], 0, 0, 0);
#pragma unroll
    for (int m = 0; m < 4; ++m) aL[m] = *(const f16x8*)&AsL[aoff[m]];
#pragma unroll
    for (int m = 0; m < 4; ++m)
#pragma unroll
      for (int n = 0; n < 4; ++n)
        acc[m][n] = __builtin_amdgcn_mfma_f32_16x16x32_f16(aL[m], bH[n],
                                                           acc[m][n], 0, 0, 0);
  }
  const int crow = (lane >> 4) << 2;
  const int ccol = lane & 15;
  const int col0 = blockIdx.x * BN;
#pragma unroll
  for (int n = 0; n < 4; ++n) {
    const int gc = col0 + wc + n * 16 + ccol;
    const float bias = b1[gc];
#pragma unroll
    for (int m = 0; m < 4; ++m) {
      const int gr = row0 + wr + m * 16 + crow;
#pragma unroll
      for (int j = 0; j < 4; ++j)
        h[(size_t)(gr + j) * HID + gc] = fmaxf(acc[m][n][j] + bias, 0.f);
    }
  }
}

// ---------------------------------------------------------------------------
// Tail GEMM (path A): noise A-frags from the pre-split x image; main loop
// reads h fp32 + in-register split. K-split x4; grid (128, 4).
// ---------------------------------------------------------------------------
__global__ __launch_bounds__(256) void k_tail_gemm_x(
    const _Float16* __restrict__ ximgH, const _Float16* __restrict__ ximgL,
    const float* __restrict__ h, const _Float16* __restrict__ w2h,
    const _Float16* __restrict__ w2l, const _Float16* __restrict__ nwh,
    const _Float16* __restrict__ nwl, float* __restrict__ partsN,
    float* __restrict__ partsM) {
  const int tid = threadIdx.x;
  const int lane = tid & 63;
  const int w = tid >> 6;
  const int kc = blockIdx.y;  // 0..3
  const int r0 = blockIdx.x * 64 + w * 16;
  const int fr = lane & 15;
  const int kg = lane >> 4;

  f32x4 acc[4], accn[4];
  const f32x4 zero = {0.f, 0.f, 0.f, 0.f};
#pragma unroll
  for (int n = 0; n < 4; ++n) {
    acc[n] = zero;
    accn[n] = zero;
  }

  {
    const int row = r0 + fr;
    const int ar = row & 127;
    const int sw = (ar >> 1) & 3;
    const size_t rowbase =
        (size_t)(row >> 7) * (IN_DIM / 32) * 4096 + ar * 32 + ((kg ^ sw) << 3);
    const int kb = kc * 1024;
    for (int k0 = 0; k0 < 1024; k0 += 32) {
      const size_t off = rowbase + (size_t)((kb + k0) >> 5) * 4096;
      const f16x8 ah = *(const f16x8*)&ximgH[off];
      const f16x8 al = *(const f16x8*)&ximgL[off];
#pragma unroll
      for (int n = 0; n < 4; ++n) {
        const size_t boffs =
            (size_t)(n * 16 + fr) * IN_DIM + kb + k0 + (kg << 3);
        const f16x8 bh = *(const f16x8*)&nwh[boffs];
        const f16x8 bl = *(const f16x8*)&nwl[boffs];
        accn[n] =
            __builtin_amdgcn_mfma_f32_16x16x32_f16(ah, bh, accn[n], 0, 0, 0);
        accn[n] =
            __builtin_amdgcn_mfma_f32_16x16x32_f16(al, bh, accn[n], 0, 0, 0);
        accn[n] =
            __builtin_amdgcn_mfma_f32_16x16x32_f16(ah, bl, accn[n], 0, 0, 0);
      }
    }
  }

  {
    const int kb = kc * 512;
    const float* hrow = &h[(size_t)(r0 + fr) * HID + kb + (kg << 3)];
    for (int k0 = 0; k0 < 512; k0 += 32) {
      const float4 f0 = *(const float4*)&hrow[k0];
      const float4 f1 = *(const float4*)&hrow[k0 + 4];
      const float fv[8] = {f0.x, f0.y, f0.z, f0.w, f1.x, f1.y, f1.z, f1.w};
      f16x8 ah, al;
#pragma unroll
      for (int j = 0; j < 8; ++j) {
        const _Float16 hi = (_Float16)fv[j];
        ah[j] = hi;
        al[j] = (_Float16)(fv[j] - (float)hi);
      }
#pragma unroll
      for (int n = 0; n < 4; ++n) {
        const size_t boffs = (size_t)(n * 16 + fr) * HID + kb + k0 + (kg << 3);
        const f16x8 bh = *(const f16x8*)&w2h[boffs];
        const f16x8 bl = *(const f16x8*)&w2l[boffs];
        acc[n] = __builtin_amdgcn_mfma_f32_16x16x32_f16(ah, bh, acc[n], 0, 0, 0);
        acc[n] = __builtin_amdgcn_mfma_f32_16x16x32_f16(al, bh, acc[n], 0, 0, 0);
        acc[n] = __builtin_amdgcn_mfma_f32_16x16x32_f16(ah, bl, acc[n], 0, 0, 0);
      }
    }
  }

#pragma unroll
  for (int n = 0; n < 4; ++n) {
#pragma unroll
    for (int j = 0; j < 4; ++j) {
      const int row = r0 + (kg << 2) + j;
      const int col = n * 16 + fr;
      partsN[((size_t)kc * B_TOK + row) * NE + col] = accn[n][j];
      partsM[((size_t)kc * B_TOK + row) * NE + col] = acc[n][j];
    }
  }
}

// ---------------------------------------------------------------------------
// Tail GEMM (path B, R5-proven): x fp32 + in-register split.
// ---------------------------------------------------------------------------
__global__ __launch_bounds__(256) void k_tail_gemm(
    const float* __restrict__ x, const float* __restrict__ h,
    const _Float16* __restrict__ w2h, const _Float16* __restrict__ w2l,
    const _Float16* __restrict__ nwh, const _Float16* __restrict__ nwl,
    float* __restrict__ partsN, float* __restrict__ partsM) {
  const int tid = threadIdx.x;
  const int lane = tid & 63;
  const int w = tid >> 6;
  const int kc = blockIdx.y;
  const int r0 = blockIdx.x * 64 + w * 16;
  const int fr = lane & 15;
  const int kg = lane >> 4;

  f32x4 acc[4], accn[4];
  const f32x4 zero = {0.f, 0.f, 0.f, 0.f};
#pragma unroll
  for (int n = 0; n < 4; ++n) {
    acc[n] = zero;
    accn[n] = zero;
  }
  {
    const int kb = kc * 1024;
    const float* xrow = &x[(size_t)(r0 + fr) * IN_DIM + kb + (kg << 3)];
    for (int k0 = 0; k0 < 1024; k0 += 32) {
      const float4 f0 = *(const float4*)&xrow[k0];
      const float4 f1 = *(const float4*)&xrow[k0 + 4];
      const float fv[8] = {f0.x, f0.y, f0.z, f0.w, f1.x, f1.y, f1.z, f1.w};
      f16x8 ah, al;
#pragma unroll
      for (int j = 0; j < 8; ++j) {
        const _Float16 hi = (_Float16)fv[j];
        ah[j] = hi;
        al[j] = (_Float16)(fv[j] - (float)hi);
      }
#pragma unroll
      for (int n = 0; n < 4; ++n) {
        const size_t boffs =
            (size_t)(n * 16 + fr) * IN_DIM + kb + k0 + (kg << 3);
        const f16x8 bh = *(const f16x8*)&nwh[boffs];
        const f16x8 bl = *(const f16x8*)&nwl[boffs];
        accn[n] =
            __builtin_amdgcn_mfma_f32_16x16x32_f16(ah, bh, accn[n], 0, 0, 0);
        accn[n] =
            __builtin_amdgcn_mfma_f32_16x16x32_f16(al, bh, accn[n], 0, 0, 0);
        accn[n] =
            __builtin_amdgcn_mfma_f32_16x16x32_f16(ah, bl, accn[n], 0, 0, 0);
      }
    }
  }
  {
    const int kb = kc * 512;
    const float* hrow = &h[(size_t)(r0 + fr) * HID + kb + (kg << 3)];
    for (int k0 = 0; k0 < 512; k0 += 32) {
      const float4 f0 = *(const float4*)&hrow[k0];
      const float4 f1 = *(const float4*)&hrow[k0 + 4];
      const float fv[8] = {f0.x, f0.y, f0.z, f0.w, f1.x, f1.y, f1.z, f1.w};
      f16x8 ah, al;
#pragma unroll
      for (int j = 0; j < 8; ++j) {
        const _Float16 hi = (_Float16)fv[j];
        ah[j] = hi;
        al[j] = (_Float16)(fv[j] - (float)hi);
      }
#pragma unroll
      for (int n = 0; n < 4; ++n) {
        const size_t boffs = (size_t)(n * 16 + fr) * HID + kb + k0 + (kg << 3);
        const f16x8 bh = *(const f16x8*)&w2h[boffs];
        const f16x8 bl = *(const f16x8*)&w2l[boffs];
        acc[n] = __builtin_amdgcn_mfma_f32_16x16x32_f16(ah, bh, acc[n], 0, 0, 0);
        acc[n] = __builtin_amdgcn_mfma_f32_16x16x32_f16(al, bh, acc[n], 0, 0, 0);
        acc[n] = __builtin_amdgcn_mfma_f32_16x16x32_f16(ah, bl, acc[n], 0, 0, 0);
      }
    }
  }
#pragma unroll
  for (int n = 0; n < 4; ++n) {
#pragma unroll
    for (int j = 0; j < 4; ++j) {
      const int row = r0 + (kg << 2) + j;
      const int col = n * 16 + fr;
      partsN[((size_t)kc * B_TOK + row) * NE + col] = accn[n][j];
      partsM[((size_t)kc * B_TOK + row) * NE + col] = acc[n][j];
    }
  }
}

// ---------------------------------------------------------------------------
// Tail finish: sum k-chunks, logits, softmax, ew + column partials.
// ---------------------------------------------------------------------------
__global__ __launch_bounds__(256) void k_tail_fin(
    const float* __restrict__ partsN, const float* __restrict__ partsM,
    const float* __restrict__ b2, const float* __restrict__ neps,
    float* __restrict__ ew, float* __restrict__ partials) {
  __shared__ float psum[4][NE];
  const int tid = threadIdx.x;
  const int lane = tid & 63;
  const int w = tid >> 6;
  const int r0 = blockIdx.x * 64 + w * 16;
  const int fr = lane & 15;
  const int kg = lane >> 4;

  f32x4 acc[4];
#pragma unroll
  for (int n = 0; n < 4; ++n) {
#pragma unroll
    for (int j = 0; j < 4; ++j) {
      const int row = r0 + (kg << 2) + j;
      const int col = n * 16 + fr;
      float nz = 0.f, a = 0.f;
#pragma unroll
      for (int kc = 0; kc < 4; ++kc) {
        nz += partsN[((size_t)kc * B_TOK + row) * NE + col];
        a += partsM[((size_t)kc * B_TOK + row) * NE + col];
      }
      acc[n][j] = a + b2[col] + neps[(size_t)row * NE + col] * nz;
    }
  }

  float colpart[4] = {0.f, 0.f, 0.f, 0.f};
#pragma unroll
  for (int j = 0; j < 4; ++j) {
    float m = fmaxf(fmaxf(acc[0][j], acc[1][j]), fmaxf(acc[2][j], acc[3][j]));
#pragma unroll
    for (int o = 8; o > 0; o >>= 1) m = fmaxf(m, __shfl_xor(m, o));
    float e[4];
    float s = 0.f;
#pragma unroll
    for (int n = 0; n < 4; ++n) {
      e[n] = __expf(acc[n][j] - m);
      s += e[n];
    }
#pragma unroll
    for (int o = 8; o > 0; o >>= 1) s += __shfl_xor(s, o);
    const int row = r0 + (kg << 2) + j;
#pragma unroll
    for (int n = 0; n < 4; ++n) {
      const float p = e[n] / s;
      ew[(size_t)row * NE + n * 16 + fr] = p;
      colpart[n] += p;
    }
  }
#pragma unroll
  for (int n = 0; n < 4; ++n) {
    colpart[n] += __shfl_xor(colpart[n], 16);
    colpart[n] += __shfl_xor(colpart[n], 32);
  }
  if (lane < 16) {
#pragma unroll
    for (int n = 0; n < 4; ++n) psum[w][n * 16 + lane] = colpart[n];
  }
  __syncthreads();
  if (tid < NE) {
    partials[(size_t)blockIdx.x * NE + tid] =
        psum[0][tid] + psum[1][tid] + psum[2][tid] + psum[3][tid];
  }
}

// ---------------------------------------------------------------------------
// mask from running totals (single block, deterministic)
// ---------------------------------------------------------------------------
__global__ void k_mask(const float* __restrict__ partials,
                       const float* __restrict__ total_prev,
                       float* __restrict__ maskbuf, int nblocks) {
  const int e = threadIdx.x;
  float t = total_prev[e];
  for (int b = 0; b < nblocks; ++b) t += partials[b * NE + e];
  float s = t;
#pragma unroll
  for (int o = 32; o > 0; o >>= 1) s += __shfl_xor(s, o);
  const float mean = s * (1.f / 64.f);
  maskbuf[e] = (t - mean > 0.f) ? 0.f : 1.f;
}

// ---------------------------------------------------------------------------
// mask + top-8 (ties keep larger index) + renormalizing softmax
// ---------------------------------------------------------------------------
__global__ __launch_bounds__(256) void k_final(
    const float* __restrict__ ew, const float* __restrict__ maskbuf,
    float* __restrict__ out) {
  const int tid = threadIdx.x;
  const int lane = tid & 63;
  const int row = (blockIdx.x << 2) + (tid >> 6);
  const float v = ew[row * NE + lane] * maskbuf[lane];
  int rank = 0;
#pragma unroll
  for (int j = 0; j < 64; ++j) {
    const float vj = __shfl(v, j);
    rank += (vj > v) || (vj == v && j > lane);
  }
  const bool keep = rank < TOPK;
  float m = keep ? v : -INFINITY;
#pragma unroll
  for (int o = 32; o > 0; o >>= 1) m = fmaxf(m, __shfl_xor(m, o));
  const float e = keep ? __expf(v - m) : 0.f;
  float s = e;
#pragma unroll
  for (int o = 32; o > 0; o >>= 1) s += __shfl_xor(s, o);
  out[row * NE + lane] = e / s;
}

// ---------------------------------------------------------------------------
extern "C" void kernel_launch(void* const* d_in, const int* in_sizes, int n_in,
                              void* d_out, int out_size, void* d_ws,
                              size_t ws_size, hipStream_t stream) {
  const float* x = (const float*)d_in[0];
  const float* W1 = (const float*)d_in[1];
  const float* b1 = (const float*)d_in[2];
  const float* W2 = (const float*)d_in[3];
  const float* b2 = (const float*)d_in[4];
  const float* nw = (const float*)d_in[5];
  const float* neps = (const float*)d_in[6];
  const float* tprev = (const float*)d_in[7];
  float* out = (float*)d_out;

  char* ws = (char*)d_ws;
  const size_t sz_h = (size_t)B_TOK * HID * 4;          // 64 MB
  const size_t sz_w1p = (size_t)HID * IN_DIM * 2;       // 16 MB per plane
  const size_t sz_xp = (size_t)B_TOK * IN_DIM * 2;      // 64 MB per plane
  const size_t sz_parts = (size_t)4 * B_TOK * NE * 4;   // 8 MB each
  const size_t sz_w2s = (size_t)NE * HID * 2;
  const size_t sz_nws = (size_t)NE * IN_DIM * 2;
  const size_t sz_ew = (size_t)B_TOK * NE * 4;
  const size_t sz_small = 2 * sz_w2s + 2 * sz_nws + sz_ew + 129 * NE * 4 + 256;
  const size_t need_A =
      sz_h + 2 * sz_w1p + 2 * sz_xp + 2 * sz_parts + sz_small;  // ~244 MB

  if (ws_size >= need_A) {
    // ---- path A: images + A-in-register pipelined gemm1 ----
    float* h = (float*)ws;
    _Float16* w1ih = (_Float16*)(ws + sz_h);
    _Float16* w1il = (_Float16*)(ws + sz_h + sz_w1p);
    _Float16* ximgH = (_Float16*)(ws + sz_h + 2 * sz_w1p);
    _Float16* ximgL = (_Float16*)(ws + sz_h + 2 * sz_w1p + sz_xp);
    char* rest = ws + sz_h + 2 * sz_w1p + 2 * sz_xp;
    float* partsN = (float*)rest;
    float* partsM = (float*)(rest + sz_parts);
    _Float16* w2h = (_Float16*)(rest + 2 * sz_parts);
    _Float16* w2l = w2h + (size_t)NE * HID;
    _Float16* nwh = w2l + (size_t)NE * HID;
    _Float16* nwl = nwh + (size_t)NE * IN_DIM;
    float* ewbuf = (float*)(nwl + (size_t)NE * IN_DIM);
    float* partials = ewbuf + (size_t)B_TOK * NE;
    float* maskbuf = partials + 128 * NE;

    k_prep_w<<<128, 256, 0, stream>>>(W2, nw, w2h, w2l, nwh, nwl);
    k_prep_w1img<<<dim3(HID / BN, IN_DIM / BK), 256, 0, stream>>>(W1, w1ih,
                                                                  w1il);
    k_prep_ximg<<<dim3(B_TOK / BM, IN_DIM / BK), 256, 0, stream>>>(x, ximgH,
                                                                   ximgL);
    k_gemm1_reg<<<(HID / BN) * (B_TOK / BM), 256, 0, stream>>>(
        ximgH, ximgL, w1ih, w1il, b1, h);
    k_tail_gemm_x<<<dim3(B_TOK / 64, 4), 256, 0, stream>>>(
        ximgH, ximgL, h, w2h, w2l, nwh, nwl, partsN, partsM);
    k_tail_fin<<<B_TOK / 64, 256, 0, stream>>>(partsN, partsM, b2, neps, ewbuf,
                                               partials);
    k_mask<<<1, 64, 0, stream>>>(partials, tprev, maskbuf, B_TOK / 64);
    k_final<<<B_TOK / 4, 256, 0, stream>>>(ewbuf, maskbuf, out);
  } else {
    // ---- path B: R5-proven fast path (~117 MB ws, known to fit) ----
    float* h = (float*)ws;
    _Float16* w1ih = (_Float16*)(ws + sz_h);
    _Float16* w1il = (_Float16*)(ws + sz_h + sz_w1p);
    char* rest = ws + sz_h + 2 * sz_w1p;
    float* partsN = (float*)rest;
    float* partsM = (float*)(rest + sz_parts);
    _Float16* w2h = (_Float16*)(rest + 2 * sz_parts);
    _Float16* w2l = w2h + (size_t)NE * HID;
    _Float16* nwh = w2l + (size_t)NE * HID;
    _Float16* nwl = nwh + (size_t)NE * IN_DIM;
    float* ewbuf = (float*)(nwl + (size_t)NE * IN_DIM);
    float* partials = ewbuf + (size_t)B_TOK * NE;
    float* maskbuf = partials + 128 * NE;

    k_prep_w<<<128, 256, 0, stream>>>(W2, nw, w2h, w2l, nwh, nwl);
    k_prep_w1img<<<dim3(HID / BN, IN_DIM / BK), 256, 0, stream>>>(W1, w1ih,
                                                                  w1il);
    k_gemm1_img<<<dim3(HID / BN, B_TOK / BM), 256, 0, stream>>>(x, w1ih, w1il,
                                                                b1, h);
    k_tail_gemm<<<dim3(B_TOK / 64, 4), 256, 0, stream>>>(x, h, w2h, w2l, nwh,
                                                         nwl, partsN, partsM);
    k_tail_fin<<<B_TOK / 64, 256, 0, stream>>>(partsN, partsM, b2, neps, ewbuf,
                                               partials);
    k_mask<<<1, 64, 0, stream>>>(partials, tprev, maskbuf, B_TOK / 64);
    k_final<<<B_TOK / 4, 256, 0, stream>>>(ewbuf, maskbuf, out);
  }
}

// Round 9
// 525.630 us; speedup vs baseline: 1.1938x; 1.1938x over previous
//
#include <hip/hip_runtime.h>
#include <hip/hip_bf16.h>
#include <math.h>

// Problem constants (fixed by the reference)
#define B_TOK 8192
#define IN_DIM 4096
#define HID 2048
#define NE 64
#define TOPK 8

typedef __attribute__((ext_vector_type(8))) _Float16 f16x8;
typedef __attribute__((ext_vector_type(4))) float f32x4;

#define AS1 __attribute__((address_space(1)))
#define AS3 __attribute__((address_space(3)))

#define BM 128
#define BN 128
#define BK 32

// ---------------------------------------------------------------------------
// Prep: split W2 [2048,64] and nw [4096,64] into fp16 hi/lo, transposed to
// [col][k]. Blocks 0-63: W2 col; blocks 64-127: nw col.
// ---------------------------------------------------------------------------
__global__ __launch_bounds__(256) void k_prep_w(
    const float* __restrict__ W2, const float* __restrict__ nw,
    _Float16* __restrict__ w2h, _Float16* __restrict__ w2l,
    _Float16* __restrict__ nwh, _Float16* __restrict__ nwl) {
  const int b = blockIdx.x;
  if (b < NE) {
    const int c = b;
    for (int k = threadIdx.x; k < HID; k += 256) {
      const float v = W2[(size_t)k * NE + c];
      const _Float16 hi = (_Float16)v;
      w2h[(size_t)c * HID + k] = hi;
      w2l[(size_t)c * HID + k] = (_Float16)(v - (float)hi);
    }
  } else {
    const int c = b - NE;
    for (int k = threadIdx.x; k < IN_DIM; k += 256) {
      const float v = nw[(size_t)k * NE + c];
      const _Float16 hi = (_Float16)v;
      nwh[(size_t)c * IN_DIM + k] = hi;
      nwl[(size_t)c * IN_DIM + k] = (_Float16)(v - (float)hi);
    }
  }
}

// ---------------------------------------------------------------------------
// Prep: W1 image — split fp16 hi/lo, tiled per (128-colblk c, ktile kt),
// swizzled exactly like the Bs LDS layout:
//   img[(c*128 + kt)*4096 + n*32 + ((g ^ sw(n))<<3) + j]
//     = split(W1[kt*32 + g*8 + j][c*128 + n]),  sw(n) = (n>>1)&3.
// ---------------------------------------------------------------------------
__global__ __launch_bounds__(256) void k_prep_w1img(
    const float* __restrict__ W1, _Float16* __restrict__ imgH,
    _Float16* __restrict__ imgL) {
  const int c = blockIdx.x;   // 0..15
  const int kt = blockIdx.y;  // 0..127
  const int tid = threadIdx.x;
  const int n = tid & 127;
  const int g0 = tid >> 7;  // 0..1
  const size_t base = ((size_t)c * (IN_DIM / 32) + kt) * 4096;
  const int sw = (n >> 1) & 3;
#pragma unroll
  for (int gi = 0; gi < 2; ++gi) {
    const int g = g0 * 2 + gi;  // 0..3
    const float* src = &W1[(size_t)(kt * 32 + g * 8) * HID + c * 128 + n];
    f16x8 vh, vl;
#pragma unroll
    for (int j = 0; j < 8; ++j) {
      const float v = src[(size_t)j * HID];
      const _Float16 hi = (_Float16)v;
      vh[j] = hi;
      vl[j] = (_Float16)(v - (float)hi);
    }
    const size_t off = base + n * 32 + ((g ^ sw) << 3);
    *(f16x8*)&imgH[off] = vh;
    *(f16x8*)&imgL[off] = vl;
  }
}

// ---------------------------------------------------------------------------
// Prep: x image — split fp16 hi/lo, tiled per (128-rowblk rb, ktile kt),
// swizzled exactly like the As LDS layout (also the per-lane A-frag layout).
// ---------------------------------------------------------------------------
__global__ __launch_bounds__(256) void k_prep_ximg(
    const float* __restrict__ x, _Float16* __restrict__ imgH,
    _Float16* __restrict__ imgL) {
  const int rb = blockIdx.x;  // 0..63
  const int kt = blockIdx.y;  // 0..127
  const int tid = threadIdx.x;
  const int ar = tid >> 1;    // 0..127
  const int half = tid & 1;   // 0..1
  const size_t base = ((size_t)rb * (IN_DIM / 32) + kt) * 4096;
  const int sw = (ar >> 1) & 3;
  const float* src = &x[(size_t)(rb * 128 + ar) * IN_DIM + kt * 32 + half * 16];
#pragma unroll
  for (int gi = 0; gi < 2; ++gi) {
    const int g = half * 2 + gi;  // 0..3
    const float4 f0 = *(const float4*)(src + gi * 8);
    const float4 f1 = *(const float4*)(src + gi * 8 + 4);
    const float fv[8] = {f0.x, f0.y, f0.z, f0.w, f1.x, f1.y, f1.z, f1.w};
    f16x8 vh, vl;
#pragma unroll
    for (int j = 0; j < 8; ++j) {
      const _Float16 hi = (_Float16)fv[j];
      vh[j] = hi;
      vl[j] = (_Float16)(fv[j] - (float)hi);
    }
    const size_t off = base + ar * 32 + ((g ^ sw) << 3);
    *(f16x8*)&imgH[off] = vh;
    *(f16x8*)&imgL[off] = vl;
  }
}

// ---------------------------------------------------------------------------
// GEMM1 (path A): 256x256 tile, BK=32, 512 threads = 8 waves (2Mx4N),
// per-wave 128x64 output (8x4 16x16x32 frags). Same verified 2-phase dbuf +
// counted vmcnt(8) + raw-barrier schedule as R7, but 2x arithmetic intensity
// (96 MFMA per barrier-pair per wave; 12 MFMA/KB staged vs 6).
// A/B staged via global_load_lds from the pre-split swizzled images; a
// 256-wide tile = two 128-wide image subtiles. LDS 128 KB; 1 block/CU,
// grid = 256 = #CUs. XCD swizzle: 8 XCDs x 32 chunks.
// ---------------------------------------------------------------------------
#define WAITVM8() asm volatile("s_waitcnt vmcnt(8)" ::: "memory")
#define WAITVM0() asm volatile("s_waitcnt vmcnt(0)" ::: "memory")
#define BAR()                      \
  do {                             \
    asm volatile("" ::: "memory"); \
    __builtin_amdgcn_s_barrier();  \
    asm volatile("" ::: "memory"); \
  } while (0)

__global__ __launch_bounds__(512, 2) void k_gemm1_256(
    const _Float16* __restrict__ ximgH, const _Float16* __restrict__ ximgL,
    const _Float16* __restrict__ w1ih, const _Float16* __restrict__ w1il,
    const float* __restrict__ b1, float* __restrict__ h) {
  // [2 subtiles][128 rows][32 k] per plane = 8192 f16 = 16 KB each
  __shared__ _Float16 AsH0[8192], AsL0[8192], BsH0[8192], BsL0[8192];
  __shared__ _Float16 AsH1[8192], AsL1[8192], BsH1[8192], BsL1[8192];

  const int tid = threadIdx.x;
  const int lane = tid & 63;
  const int w = tid >> 6;        // 0..7
  const int wr = (w >> 2) << 7;  // 0 or 128
  const int wc = (w & 3) << 6;   // 0,64,128,192

  // XCD swizzle: 256 blocks = 8 XCDs x 32-chunk
  const int f = blockIdx.x;
  const int L = (f & 7) * 32 + (f >> 3);
  const int brow = L >> 3;  // 0..31 (256-row panel)
  const int bcol = L & 7;   // 0..7  (256-col panel)
  const int row0 = brow * 256;
  const int col0 = bcol * 256;

  const int fr = lane & 15;
  const int kg = lane >> 4;
  int aoff[8], boff[4];
#pragma unroll
  for (int m = 0; m < 8; ++m) {
    const int r = wr + m * 16 + fr;  // 0..255
    aoff[m] = (r >> 7) * 4096 + (r & 127) * 32 + ((kg ^ ((r >> 1) & 3)) << 3);
  }
#pragma unroll
  for (int n = 0; n < 4; ++n) {
    const int c = wc + n * 16 + fr;  // 0..255
    boff[n] = (c >> 7) * 4096 + (c & 127) * 32 + ((kg ^ ((c >> 1) & 3)) << 3);
  }

  // Global staging bases (bytes), per plane x 128-subtile; +tid*16 lane slot.
  const size_t tstep = (size_t)(IN_DIM / 32) * 4096 * 2;  // bytes per 128-blk
  const char* pah0 = (const char*)ximgH + (size_t)(2 * brow) * tstep + (tid << 4);
  const char* pah1 = pah0 + tstep;
  const char* pal0 = (const char*)ximgL + (size_t)(2 * brow) * tstep + (tid << 4);
  const char* pal1 = pal0 + tstep;
  const char* pbh0 = (const char*)w1ih + (size_t)(2 * bcol) * tstep + (tid << 4);
  const char* pbh1 = pbh0 + tstep;
  const char* pbl0 = (const char*)w1il + (size_t)(2 * bcol) * tstep + (tid << 4);
  const char* pbl1 = pbl0 + tstep;

#define GL1(srcp, dstbuf, dstoff)                                     \
  __builtin_amdgcn_global_load_lds(                                   \
      (const AS1 unsigned int*)((srcp) + _tb),                        \
      (AS3 unsigned int*)((char*)(dstbuf) + (dstoff) + (tid << 4)),   \
      16, 0, 0)

#define STAGE(AH, AL, BH, BL, kt)          \
  do {                                     \
    const size_t _tb = (size_t)(kt) * 8192; \
    GL1(pah0, AH, 0);                      \
    GL1(pah1, AH, 8192);                   \
    GL1(pal0, AL, 0);                      \
    GL1(pal1, AL, 8192);                   \
    GL1(pbh0, BH, 0);                      \
    GL1(pbh1, BH, 8192);                   \
    GL1(pbl0, BL, 0);                      \
    GL1(pbl1, BL, 8192);                   \
  } while (0)

  f32x4 acc[8][4];
  const f32x4 zero = {0.f, 0.f, 0.f, 0.f};
#pragma unroll
  for (int m = 0; m < 8; ++m)
#pragma unroll
    for (int n = 0; n < 4; ++n) acc[m][n] = zero;

  // hh: a(hi)*b(hi); hl: a(hi)*b(lo); lh: a(lo)*b(hi). a[] reused for lo.
#define COMPUTE3(AH, AL, BH, BL)                                               \
  do {                                                                         \
    f16x8 a[8], b[4], bl[4];                                                   \
    _Pragma("unroll") for (int m = 0; m < 8; ++m) a[m] =                       \
        *(const f16x8*)&(AH)[aoff[m]];                                         \
    _Pragma("unroll") for (int n = 0; n < 4; ++n) b[n] =                       \
        *(const f16x8*)&(BH)[boff[n]];                                         \
    _Pragma("unroll") for (int m = 0; m < 8; ++m)                              \
        _Pragma("unroll") for (int n = 0; n < 4; ++n) acc[m][n] =              \
            __builtin_amdgcn_mfma_f32_16x16x32_f16(a[m], b[n], acc[m][n], 0,   \
                                                   0, 0);                      \
    _Pragma("unroll") for (int n = 0; n < 4; ++n) bl[n] =                      \
        *(const f16x8*)&(BL)[boff[n]];                                         \
    _Pragma("unroll") for (int m = 0; m < 8; ++m)                              \
        _Pragma("unroll") for (int n = 0; n < 4; ++n) acc[m][n] =              \
            __builtin_amdgcn_mfma_f32_16x16x32_f16(a[m], bl[n], acc[m][n], 0,  \
                                                   0, 0);                      \
    _Pragma("unroll") for (int m = 0; m < 8; ++m) a[m] =                       \
        *(const f16x8*)&(AL)[aoff[m]];                                         \
    _Pragma("unroll") for (int m = 0; m < 8; ++m)                              \
        _Pragma("unroll") for (int n = 0; n < 4; ++n) acc[m][n] =              \
            __builtin_amdgcn_mfma_f32_16x16x32_f16(a[m], b[n], acc[m][n], 0,   \
                                                   0, 0);                      \
  } while (0)

  // prologue: stage tile 0 -> buf0 (8 loads outstanding)
  STAGE(AsH0, AsL0, BsH0, BsL0, 0);

  const int NT = IN_DIM / BK;  // 128, even
  for (int t = 0; t < NT; t += 2) {
    // phase 0: prefetch t+1 -> buf1; compute t from buf0
    STAGE(AsH1, AsL1, BsH1, BsL1, t + 1);  // 16 outstanding
    WAITVM8();                             // tile-t's 8 landed (wave-local)
    BAR();                                 // all waves' tile-t data in LDS
    COMPUTE3(AsH0, AsL0, BsH0, BsL0);
    BAR();  // buf0 free
    // phase 1: prefetch t+2 -> buf0; compute t+1 from buf1
    if (t + 2 < NT) {
      STAGE(AsH0, AsL0, BsH0, BsL0, t + 2);
      WAITVM8();
    } else {
      WAITVM0();
    }
    BAR();
    COMPUTE3(AsH1, AsL1, BsH1, BsL1);
    BAR();  // buf1 free
  }

  // epilogue: bias + relu. C/D: row=(l>>4)*4+j, col=l&15 (m89-verified)
  const int crow = (lane >> 4) << 2;
  const int ccol = lane & 15;
#pragma unroll
  for (int n = 0; n < 4; ++n) {
    const int gc = col0 + wc + n * 16 + ccol;
    const float bias = b1[gc];
#pragma unroll
    for (int m = 0; m < 8; ++m) {
      const int gr = row0 + wr + m * 16 + crow;
#pragma unroll
      for (int j = 0; j < 4; ++j)
        h[(size_t)(gr + j) * HID + gc] = fmaxf(acc[m][n][j] + bias, 0.f);
    }
  }
#undef GL1
#undef STAGE
#undef COMPUTE3
}

// ---------------------------------------------------------------------------
// GEMM1 (path B, R5-proven): B via image, A converted in-kernel.
// ---------------------------------------------------------------------------
__global__ __launch_bounds__(256) void k_gemm1_img(
    const float* __restrict__ x, const _Float16* __restrict__ w1ih,
    const _Float16* __restrict__ w1il, const float* __restrict__ b1,
    float* __restrict__ h) {
  __shared__ _Float16 AsH[BM * BK];
  __shared__ _Float16 AsL[BM * BK];
  __shared__ _Float16 BsH[BN * BK];
  __shared__ _Float16 BsL[BN * BK];

  const int tid = threadIdx.x;
  const int lane = tid & 63;
  const int w = tid >> 6;
  const int wr = (w >> 1) << 6;
  const int wc = (w & 1) << 6;
  const int row0 = blockIdx.y * BM;

  const int fr = lane & 15;
  const int kg = lane >> 4;
  int aoff[4], boff[4];
#pragma unroll
  for (int m = 0; m < 4; ++m) {
    const int r = wr + m * 16 + fr;
    aoff[m] = r * BK + ((kg ^ ((r >> 1) & 3)) << 3);
  }
#pragma unroll
  for (int n = 0; n < 4; ++n) {
    const int c = wc + n * 16 + fr;
    boff[n] = c * BK + ((kg ^ ((c >> 1) & 3)) << 3);
  }

  f32x4 acc[4][4];
  const f32x4 zero = {0.f, 0.f, 0.f, 0.f};
#pragma unroll
  for (int m = 0; m < 4; ++m)
#pragma unroll
    for (int n = 0; n < 4; ++n) acc[m][n] = zero;

  for (int k0 = 0; k0 < IN_DIM; k0 += BK) {
    __syncthreads();
    {
      const size_t tb =
          (((size_t)blockIdx.x * (IN_DIM / 32) + (k0 >> 5)) * 4096) *
          sizeof(_Float16);
      const char* gh = (const char*)w1ih + tb + (lane << 4);
      const char* gl = (const char*)w1il + tb + (lane << 4);
#pragma unroll
      for (int i = 0; i < 2; ++i) {
        const int cb = ((w << 1) + i) << 10;
        __builtin_amdgcn_global_load_lds((const AS1 unsigned int*)(gh + cb),
                                         (AS3 unsigned int*)((char*)BsH + cb),
                                         16, 0, 0);
        __builtin_amdgcn_global_load_lds((const AS1 unsigned int*)(gl + cb),
                                         (AS3 unsigned int*)((char*)BsL + cb),
                                         16, 0, 0);
      }
    }
#pragma unroll
    for (int i = 0; i < 2; ++i) {
      const int ar = (tid >> 2) + i * 64;
      const int g = tid & 3;
      const float* src = &x[(size_t)(row0 + ar) * IN_DIM + k0 + (g << 3)];
      const float4 f0 = *(const float4*)src;
      const float4 f1 = *(const float4*)(src + 4);
      const float fv[8] = {f0.x, f0.y, f0.z, f0.w, f1.x, f1.y, f1.z, f1.w};
      f16x8 vh, vl;
#pragma unroll
      for (int j = 0; j < 8; ++j) {
        const _Float16 hi = (_Float16)fv[j];
        vh[j] = hi;
        vl[j] = (_Float16)(fv[j] - (float)hi);
      }
      const int off = ar * BK + (((g ^ ((ar >> 1) & 3))) << 3);
      *(f16x8*)&AsH[off] = vh;
      *(f16x8*)&AsL[off] = vl;
    }
    __syncthreads();
    f16x8 aH[4], bH[4], bL[4], aL[4];
#pragma unroll
    for (int m = 0; m < 4; ++m) aH[m] = *(const f16x8*)&AsH[aoff[m]];
#pragma unroll
    for (int n = 0; n < 4; ++n) bH[n] = *(const f16x8*)&BsH[boff[n]];
#pragma unroll
    for (int m = 0; m < 4; ++m)
#pragma unroll
      for (int n = 0; n < 4; ++n)
        acc[m][n] = __builtin_amdgcn_mfma_f32_16x16x32_f16(aH[m], bH[n],
                                                           acc[m][n], 0, 0, 0);
#pragma unroll
    for (int n = 0; n < 4; ++n) bL[n] = *(const f16x8*)&BsL[boff[n]];
#pragma unroll
    for (int m = 0; m < 4; ++m)
#pragma unroll
      for (int n = 0; n < 4; ++n)
        acc[m][n] = __builtin_amdgcn_mfma_f32_16x16x32_f16(aH[m], bL[n],
                                                           acc[m][n], 0, 0, 0);
#pragma unroll
    for (int m = 0; m < 4; ++m) aL[m] = *(const f16x8*)&AsL[aoff[m]];
#pragma unroll
    for (int m = 0; m < 4; ++m)
#pragma unroll
      for (int n = 0; n < 4; ++n)
        acc[m][n] = __builtin_amdgcn_mfma_f32_16x16x32_f16(aL[m], bH[n],
                                                           acc[m][n], 0, 0, 0);
  }
  const int crow = (lane >> 4) << 2;
  const int ccol = lane & 15;
  const int col0 = blockIdx.x * BN;
#pragma unroll
  for (int n = 0; n < 4; ++n) {
    const int gc = col0 + wc + n * 16 + ccol;
    const float bias = b1[gc];
#pragma unroll
    for (int m = 0; m < 4; ++m) {
      const int gr = row0 + wr + m * 16 + crow;
#pragma unroll
      for (int j = 0; j < 4; ++j)
        h[(size_t)(gr + j) * HID + gc] = fmaxf(acc[m][n][j] + bias, 0.f);
    }
  }
}

// ---------------------------------------------------------------------------
// Tail GEMM (path A): noise A-frags from the pre-split x image; main loop
// reads h fp32 + in-register split. K-split x4; grid (128, 4).
// ---------------------------------------------------------------------------
__global__ __launch_bounds__(256) void k_tail_gemm_x(
    const _Float16* __restrict__ ximgH, const _Float16* __restrict__ ximgL,
    const float* __restrict__ h, const _Float16* __restrict__ w2h,
    const _Float16* __restrict__ w2l, const _Float16* __restrict__ nwh,
    const _Float16* __restrict__ nwl, float* __restrict__ partsN,
    float* __restrict__ partsM) {
  const int tid = threadIdx.x;
  const int lane = tid & 63;
  const int w = tid >> 6;
  const int kc = blockIdx.y;  // 0..3
  const int r0 = blockIdx.x * 64 + w * 16;
  const int fr = lane & 15;
  const int kg = lane >> 4;

  f32x4 acc[4], accn[4];
  const f32x4 zero = {0.f, 0.f, 0.f, 0.f};
#pragma unroll
  for (int n = 0; n < 4; ++n) {
    acc[n] = zero;
    accn[n] = zero;
  }

  {
    const int row = r0 + fr;
    const int ar = row & 127;
    const int sw = (ar >> 1) & 3;
    const size_t rowbase =
        (size_t)(row >> 7) * (IN_DIM / 32) * 4096 + ar * 32 + ((kg ^ sw) << 3);
    const int kb = kc * 1024;
    for (int k0 = 0; k0 < 1024; k0 += 32) {
      const size_t off = rowbase + (size_t)((kb + k0) >> 5) * 4096;
      const f16x8 ah = *(const f16x8*)&ximgH[off];
      const f16x8 al = *(const f16x8*)&ximgL[off];
#pragma unroll
      for (int n = 0; n < 4; ++n) {
        const size_t boffs =
            (size_t)(n * 16 + fr) * IN_DIM + kb + k0 + (kg << 3);
        const f16x8 bh = *(const f16x8*)&nwh[boffs];
        const f16x8 bl = *(const f16x8*)&nwl[boffs];
        accn[n] =
            __builtin_amdgcn_mfma_f32_16x16x32_f16(ah, bh, accn[n], 0, 0, 0);
        accn[n] =
            __builtin_amdgcn_mfma_f32_16x16x32_f16(al, bh, accn[n], 0, 0, 0);
        accn[n] =
            __builtin_amdgcn_mfma_f32_16x16x32_f16(ah, bl, accn[n], 0, 0, 0);
      }
    }
  }

  {
    const int kb = kc * 512;
    const float* hrow = &h[(size_t)(r0 + fr) * HID + kb + (kg << 3)];
    for (int k0 = 0; k0 < 512; k0 += 32) {
      const float4 f0 = *(const float4*)&hrow[k0];
      const float4 f1 = *(const float4*)&hrow[k0 + 4];
      const float fv[8] = {f0.x, f0.y, f0.z, f0.w, f1.x, f1.y, f1.z, f1.w};
      f16x8 ah, al;
#pragma unroll
      for (int j = 0; j < 8; ++j) {
        const _Float16 hi = (_Float16)fv[j];
        ah[j] = hi;
        al[j] = (_Float16)(fv[j] - (float)hi);
      }
#pragma unroll
      for (int n = 0; n < 4; ++n) {
        const size_t boffs = (size_t)(n * 16 + fr) * HID + kb + k0 + (kg << 3);
        const f16x8 bh = *(const f16x8*)&w2h[boffs];
        const f16x8 bl = *(const f16x8*)&w2l[boffs];
        acc[n] = __builtin_amdgcn_mfma_f32_16x16x32_f16(ah, bh, acc[n], 0, 0, 0);
        acc[n] = __builtin_amdgcn_mfma_f32_16x16x32_f16(al, bh, acc[n], 0, 0, 0);
        acc[n] = __builtin_amdgcn_mfma_f32_16x16x32_f16(ah, bl, acc[n], 0, 0, 0);
      }
    }
  }

#pragma unroll
  for (int n = 0; n < 4; ++n) {
#pragma unroll
    for (int j = 0; j < 4; ++j) {
      const int row = r0 + (kg << 2) + j;
      const int col = n * 16 + fr;
      partsN[((size_t)kc * B_TOK + row) * NE + col] = accn[n][j];
      partsM[((size_t)kc * B_TOK + row) * NE + col] = acc[n][j];
    }
  }
}

// ---------------------------------------------------------------------------
// Tail GEMM (path B, R5-proven): x fp32 + in-register split.
// ---------------------------------------------------------------------------
__global__ __launch_bounds__(256) void k_tail_gemm(
    const float* __restrict__ x, const float* __restrict__ h,
    const _Float16* __restrict__ w2h, const _Float16* __restrict__ w2l,
    const _Float16* __restrict__ nwh, const _Float16* __restrict__ nwl,
    float* __restrict__ partsN, float* __restrict__ partsM) {
  const int tid = threadIdx.x;
  const int lane = tid & 63;
  const int w = tid >> 6;
  const int kc = blockIdx.y;
  const int r0 = blockIdx.x * 64 + w * 16;
  const int fr = lane & 15;
  const int kg = lane >> 4;

  f32x4 acc[4], accn[4];
  const f32x4 zero = {0.f, 0.f, 0.f, 0.f};
#pragma unroll
  for (int n = 0; n < 4; ++n) {
    acc[n] = zero;
    accn[n] = zero;
  }
  {
    const int kb = kc * 1024;
    const float* xrow = &x[(size_t)(r0 + fr) * IN_DIM + kb + (kg << 3)];
    for (int k0 = 0; k0 < 1024; k0 += 32) {
      const float4 f0 = *(const float4*)&xrow[k0];
      const float4 f1 = *(const float4*)&xrow[k0 + 4];
      const float fv[8] = {f0.x, f0.y, f0.z, f0.w, f1.x, f1.y, f1.z, f1.w};
      f16x8 ah, al;
#pragma unroll
      for (int j = 0; j < 8; ++j) {
        const _Float16 hi = (_Float16)fv[j];
        ah[j] = hi;
        al[j] = (_Float16)(fv[j] - (float)hi);
      }
#pragma unroll
      for (int n = 0; n < 4; ++n) {
        const size_t boffs =
            (size_t)(n * 16 + fr) * IN_DIM + kb + k0 + (kg << 3);
        const f16x8 bh = *(const f16x8*)&nwh[boffs];
        const f16x8 bl = *(const f16x8*)&nwl[boffs];
        accn[n] =
            __builtin_amdgcn_mfma_f32_16x16x32_f16(ah, bh, accn[n], 0, 0, 0);
        accn[n] =
            __builtin_amdgcn_mfma_f32_16x16x32_f16(al, bh, accn[n], 0, 0, 0);
        accn[n] =
            __builtin_amdgcn_mfma_f32_16x16x32_f16(ah, bl, accn[n], 0, 0, 0);
      }
    }
  }
  {
    const int kb = kc * 512;
    const float* hrow = &h[(size_t)(r0 + fr) * HID + kb + (kg << 3)];
    for (int k0 = 0; k0 < 512; k0 += 32) {
      const float4 f0 = *(const float4*)&hrow[k0];
      const float4 f1 = *(const float4*)&hrow[k0 + 4];
      const float fv[8] = {f0.x, f0.y, f0.z, f0.w, f1.x, f1.y, f1.z, f1.w};
      f16x8 ah, al;
#pragma unroll
      for (int j = 0; j < 8; ++j) {
        const _Float16 hi = (_Float16)fv[j];
        ah[j] = hi;
        al[j] = (_Float16)(fv[j] - (float)hi);
      }
#pragma unroll
      for (int n = 0; n < 4; ++n) {
        const size_t boffs = (size_t)(n * 16 + fr) * HID + kb + k0 + (kg << 3);
        const f16x8 bh = *(const f16x8*)&w2h[boffs];
        const f16x8 bl = *(const f16x8*)&w2l[boffs];
        acc[n] = __builtin_amdgcn_mfma_f32_16x16x32_f16(ah, bh, acc[n], 0, 0, 0);
        acc[n] = __builtin_amdgcn_mfma_f32_16x16x32_f16(al, bh, acc[n], 0, 0, 0);
        acc[n] = __builtin_amdgcn_mfma_f32_16x16x32_f16(ah, bl, acc[n], 0, 0, 0);
      }
    }
  }
#pragma unroll
  for (int n = 0; n < 4; ++n) {
#pragma unroll
    for (int j = 0; j < 4; ++j) {
      const int row = r0 + (kg << 2) + j;
      const int col = n * 16 + fr;
      partsN[((size_t)kc * B_TOK + row) * NE + col] = accn[n][j];
      partsM[((size_t)kc * B_TOK + row) * NE + col] = acc[n][j];
    }
  }
}

// ---------------------------------------------------------------------------
// Tail finish: sum k-chunks, logits, softmax, ew + column partials.
// ---------------------------------------------------------------------------
__global__ __launch_bounds__(256) void k_tail_fin(
    const float* __restrict__ partsN, const float* __restrict__ partsM,
    const float* __restrict__ b2, const float* __restrict__ neps,
    float* __restrict__ ew, float* __restrict__ partials) {
  __shared__ float psum[4][NE];
  const int tid = threadIdx.x;
  const int lane = tid & 63;
  const int w = tid >> 6;
  const int r0 = blockIdx.x * 64 + w * 16;
  const int fr = lane & 15;
  const int kg = lane >> 4;

  f32x4 acc[4];
#pragma unroll
  for (int n = 0; n < 4; ++n) {
#pragma unroll
    for (int j = 0; j < 4; ++j) {
      const int row = r0 + (kg << 2) + j;
      const int col = n * 16 + fr;
      float nz = 0.f, a = 0.f;
#pragma unroll
      for (int kc = 0; kc < 4; ++kc) {
        nz += partsN[((size_t)kc * B_TOK + row) * NE + col];
        a += partsM[((size_t)kc * B_TOK + row) * NE + col];
      }
      acc[n][j] = a + b2[col] + neps[(size_t)row * NE + col] * nz;
    }
  }

  float colpart[4] = {0.f, 0.f, 0.f, 0.f};
#pragma unroll
  for (int j = 0; j < 4; ++j) {
    float m = fmaxf(fmaxf(acc[0][j], acc[1][j]), fmaxf(acc[2][j], acc[3][j]));
#pragma unroll
    for (int o = 8; o > 0; o >>= 1) m = fmaxf(m, __shfl_xor(m, o));
    float e[4];
    float s = 0.f;
#pragma unroll
    for (int n = 0; n < 4; ++n) {
      e[n] = __expf(acc[n][j] - m);
      s += e[n];
    }
#pragma unroll
    for (int o = 8; o > 0; o >>= 1) s += __shfl_xor(s, o);
    const int row = r0 + (kg << 2) + j;
#pragma unroll
    for (int n = 0; n < 4; ++n) {
      const float p = e[n] / s;
      ew[(size_t)row * NE + n * 16 + fr] = p;
      colpart[n] += p;
    }
  }
#pragma unroll
  for (int n = 0; n < 4; ++n) {
    colpart[n] += __shfl_xor(colpart[n], 16);
    colpart[n] += __shfl_xor(colpart[n], 32);
  }
  if (lane < 16) {
#pragma unroll
    for (int n = 0; n < 4; ++n) psum[w][n * 16 + lane] = colpart[n];
  }
  __syncthreads();
  if (tid < NE) {
    partials[(size_t)blockIdx.x * NE + tid] =
        psum[0][tid] + psum[1][tid] + psum[2][tid] + psum[3][tid];
  }
}

// ---------------------------------------------------------------------------
// mask from running totals (single block, deterministic)
// ---------------------------------------------------------------------------
__global__ void k_mask(const float* __restrict__ partials,
                       const float* __restrict__ total_prev,
                       float* __restrict__ maskbuf, int nblocks) {
  const int e = threadIdx.x;
  float t = total_prev[e];
  for (int b = 0; b < nblocks; ++b) t += partials[b * NE + e];
  float s = t;
#pragma unroll
  for (int o = 32; o > 0; o >>= 1) s += __shfl_xor(s, o);
  const float mean = s * (1.f / 64.f);
  maskbuf[e] = (t - mean > 0.f) ? 0.f : 1.f;
}

// ---------------------------------------------------------------------------
// mask + top-8 (ties keep larger index) + renormalizing softmax
// ---------------------------------------------------------------------------
__global__ __launch_bounds__(256) void k_final(
    const float* __restrict__ ew, const float* __restrict__ maskbuf,
    float* __restrict__ out) {
  const int tid = threadIdx.x;
  const int lane = tid & 63;
  const int row = (blockIdx.x << 2) + (tid >> 6);
  const float v = ew[row * NE + lane] * maskbuf[lane];
  int rank = 0;
#pragma unroll
  for (int j = 0; j < 64; ++j) {
    const float vj = __shfl(v, j);
    rank += (vj > v) || (vj == v && j > lane);
  }
  const bool keep = rank < TOPK;
  float m = keep ? v : -INFINITY;
#pragma unroll
  for (int o = 32; o > 0; o >>= 1) m = fmaxf(m, __shfl_xor(m, o));
  const float e = keep ? __expf(v - m) : 0.f;
  float s = e;
#pragma unroll
  for (int o = 32; o > 0; o >>= 1) s += __shfl_xor(s, o);
  out[row * NE + lane] = e / s;
}

// ---------------------------------------------------------------------------
extern "C" void kernel_launch(void* const* d_in, const int* in_sizes, int n_in,
                              void* d_out, int out_size, void* d_ws,
                              size_t ws_size, hipStream_t stream) {
  const float* x = (const float*)d_in[0];
  const float* W1 = (const float*)d_in[1];
  const float* b1 = (const float*)d_in[2];
  const float* W2 = (const float*)d_in[3];
  const float* b2 = (const float*)d_in[4];
  const float* nw = (const float*)d_in[5];
  const float* neps = (const float*)d_in[6];
  const float* tprev = (const float*)d_in[7];
  float* out = (float*)d_out;

  char* ws = (char*)d_ws;
  const size_t sz_h = (size_t)B_TOK * HID * 4;          // 64 MB
  const size_t sz_w1p = (size_t)HID * IN_DIM * 2;       // 16 MB per plane
  const size_t sz_xp = (size_t)B_TOK * IN_DIM * 2;      // 64 MB per plane
  const size_t sz_parts = (size_t)4 * B_TOK * NE * 4;   // 8 MB each
  const size_t sz_w2s = (size_t)NE * HID * 2;
  const size_t sz_nws = (size_t)NE * IN_DIM * 2;
  const size_t sz_ew = (size_t)B_TOK * NE * 4;
  const size_t sz_small = 2 * sz_w2s + 2 * sz_nws + sz_ew + 129 * NE * 4 + 256;
  const size_t need_A =
      sz_h + 2 * sz_w1p + 2 * sz_xp + 2 * sz_parts + sz_small;  // ~244 MB

  if (ws_size >= need_A) {
    // ---- path A: images + 256x256 pipelined gemm1 ----
    float* h = (float*)ws;
    _Float16* w1ih = (_Float16*)(ws + sz_h);
    _Float16* w1il = (_Float16*)(ws + sz_h + sz_w1p);
    _Float16* ximgH = (_Float16*)(ws + sz_h + 2 * sz_w1p);
    _Float16* ximgL = (_Float16*)(ws + sz_h + 2 * sz_w1p + sz_xp);
    char* rest = ws + sz_h + 2 * sz_w1p + 2 * sz_xp;
    float* partsN = (float*)rest;
    float* partsM = (float*)(rest + sz_parts);
    _Float16* w2h = (_Float16*)(rest + 2 * sz_parts);
    _Float16* w2l = w2h + (size_t)NE * HID;
    _Float16* nwh = w2l + (size_t)NE * HID;
    _Float16* nwl = nwh + (size_t)NE * IN_DIM;
    float* ewbuf = (float*)(nwl + (size_t)NE * IN_DIM);
    float* partials = ewbuf + (size_t)B_TOK * NE;
    float* maskbuf = partials + 128 * NE;

    k_prep_w<<<128, 256, 0, stream>>>(W2, nw, w2h, w2l, nwh, nwl);
    k_prep_w1img<<<dim3(HID / BN, IN_DIM / BK), 256, 0, stream>>>(W1, w1ih,
                                                                  w1il);
    k_prep_ximg<<<dim3(B_TOK / BM, IN_DIM / BK), 256, 0, stream>>>(x, ximgH,
                                                                   ximgL);
    k_gemm1_256<<<(HID / 256) * (B_TOK / 256), 512, 0, stream>>>(
        ximgH, ximgL, w1ih, w1il, b1, h);
    k_tail_gemm_x<<<dim3(B_TOK / 64, 4), 256, 0, stream>>>(
        ximgH, ximgL, h, w2h, w2l, nwh, nwl, partsN, partsM);
    k_tail_fin<<<B_TOK / 64, 256, 0, stream>>>(partsN, partsM, b2, neps, ewbuf,
                                               partials);
    k_mask<<<1, 64, 0, stream>>>(partials, tprev, maskbuf, B_TOK / 64);
    k_final<<<B_TOK / 4, 256, 0, stream>>>(ewbuf, maskbuf, out);
  } else {
    // ---- path B: R5-proven fast path (~117 MB ws, known to fit) ----
    float* h = (float*)ws;
    _Float16* w1ih = (_Float16*)(ws + sz_h);
    _Float16* w1il = (_Float16*)(ws + sz_h + sz_w1p);
    char* rest = ws + sz_h + 2 * sz_w1p;
    float* partsN = (float*)rest;
    float* partsM = (float*)(rest + sz_parts);
    _Float16* w2h = (_Float16*)(rest + 2 * sz_parts);
    _Float16* w2l = w2h + (size_t)NE * HID;
    _Float16* nwh = w2l + (size_t)NE * HID;
    _Float16* nwl = nwh + (size_t)NE * IN_DIM;
    float* ewbuf = (float*)(nwl + (size_t)NE * IN_DIM);
    float* partials = ewbuf + (size_t)B_TOK * NE;
    float* maskbuf = partials + 128 * NE;

    k_prep_w<<<128, 256, 0, stream>>>(W2, nw, w2h, w2l, nwh, nwl);
    k_prep_w1img<<<dim3(HID / BN, IN_DIM / BK), 256, 0, stream>>>(W1, w1ih,
                                                                  w1il);
    k_gemm1_img<<<dim3(HID / BN, B_TOK / BM), 256, 0, stream>>>(x, w1ih, w1il,
                                                                b1, h);
    k_tail_gemm<<<dim3(B_TOK / 64, 4), 256, 0, stream>>>(x, h, w2h, w2l, nwh,
                                                         nwl, partsN, partsM);
    k_tail_fin<<<B_TOK / 64, 256, 0, stream>>>(partsN, partsM, b2, neps, ewbuf,
                                               partials);
    k_mask<<<1, 64, 0, stream>>>(partials, tprev, maskbuf, B_TOK / 64);
    k_final<<<B_TOK / 4, 256, 0, stream>>>(ewbuf, maskbuf, out);
  }
}